// Round 1
// baseline (1249.602 us; speedup 1.0000x reference)
//
#include <hip/hip_runtime.h>
#include <math.h>

// Problem constants
#define TOKENS 32768
#define DM 4096
#define NE 64
#define BALW 0.1f

// ---------------- Kernel A: h = tanh(x @ w1^T) ----------------
// Tile: 256 tokens x 64 experts, BK=32. 256 threads, 8x8 micro-tile/thread.
// LDS stride 33 (pad +1): all inner-loop read patterns are <=2-way bank
// aliased (free on gfx950 per m136).
#define TM 256
#define BK 32
#define LDA 33

__global__ __launch_bounds__(256) void gemm_tanh_kernel(
    const float* __restrict__ x, const float* __restrict__ w1,
    float* __restrict__ h) {
  __shared__ float As[TM * LDA];   // 33792 B
  __shared__ float Ws[NE * LDA];   // 8448 B
  const int tid = threadIdx.x;
  const int row0 = blockIdx.x * TM;
  const int ty = tid >> 3;  // 0..31 : token group (8 tokens)
  const int tx = tid & 7;   // 0..7  : expert group (8 experts)

  float acc[8][8];
#pragma unroll
  for (int m = 0; m < 8; ++m)
#pragma unroll
    for (int n = 0; n < 8; ++n) acc[m][n] = 0.f;

  const int lr = tid >> 3;  // staging row-in-pass (0..31)
  const int lc = tid & 7;   // staging float4 col (0..7)

  for (int kc = 0; kc < DM; kc += BK) {
    __syncthreads();
    // stage x tile: 256 rows x 32 cols (coalesced: 8 lanes x 128B per row)
#pragma unroll
    for (int p = 0; p < 8; ++p) {
      const int r = p * 32 + lr;
      const float4 v = *reinterpret_cast<const float4*>(
          &x[(size_t)(row0 + r) * DM + kc + lc * 4]);
      float* dst = &As[r * LDA + lc * 4];
      dst[0] = v.x; dst[1] = v.y; dst[2] = v.z; dst[3] = v.w;
    }
    // stage w1 tile: 64 rows x 32 cols
#pragma unroll
    for (int q = 0; q < 2; ++q) {
      const int idx4 = tid * 2 + q;  // 0..511
      const int r = idx4 >> 3;       // 0..63
      const int c = idx4 & 7;
      const float4 v = *reinterpret_cast<const float4*>(
          &w1[(size_t)r * DM + kc + c * 4]);
      float* dst = &Ws[r * LDA + c * 4];
      dst[0] = v.x; dst[1] = v.y; dst[2] = v.z; dst[3] = v.w;
    }
    __syncthreads();
#pragma unroll 8
    for (int k = 0; k < BK; ++k) {
      float a[8], b[8];
#pragma unroll
      for (int m = 0; m < 8; ++m) a[m] = As[(ty * 8 + m) * LDA + k];
#pragma unroll
      for (int n = 0; n < 8; ++n) b[n] = Ws[(tx * 8 + n) * LDA + k];
#pragma unroll
      for (int m = 0; m < 8; ++m)
#pragma unroll
        for (int n = 0; n < 8; ++n) acc[m][n] = fmaf(a[m], b[n], acc[m][n]);
    }
  }
  // epilogue: tanh + store (n is contiguous -> coalesced within lanes)
#pragma unroll
  for (int m = 0; m < 8; ++m) {
    const size_t r = (size_t)(row0 + ty * 8 + m);
#pragma unroll
    for (int n = 0; n < 8; ++n) {
      h[r * NE + tx * 8 + n] = tanhf(acc[m][n]);
    }
  }
}

// ---------------- Kernel B: gate (logits, softmax, argmax) ----------------
// 128 tokens/block, thread-per-token. h and noise staged in LDS (pad 65 ->
// 2-way bank aliasing, free). w2 staged transposed; read as broadcast float4
// (same address across all lanes -> conflict-free).
#define TB 128

__global__ __launch_bounds__(128) void gate_kernel(
    const float* __restrict__ h, const float* __restrict__ w2,
    const float* __restrict__ noise, float* __restrict__ out_idx,
    float* __restrict__ out_score, float* __restrict__ imp_part,
    float* __restrict__ load_part) {
  __shared__ float hs[TB * 65];
  __shared__ float ns[TB * 65];
  __shared__ float w2t[NE * NE];  // w2t[e*64 + e'] = w2[e'][e]
  __shared__ int hist[NE];
  const int tid = threadIdx.x;
  const int t0 = blockIdx.x * TB;

  // stage h & noise (coalesced global float4 reads)
#pragma unroll
  for (int j = 0; j < 16; ++j) {
    const int f = tid + TB * j;  // float4 index 0..2047
    const int r = f >> 4;
    const int c = f & 15;
    const float4 v =
        *reinterpret_cast<const float4*>(&h[(size_t)(t0 + r) * NE + c * 4]);
    float* d = &hs[r * 65 + c * 4];
    d[0] = v.x; d[1] = v.y; d[2] = v.z; d[3] = v.w;
    const float4 u = *reinterpret_cast<const float4*>(
        &noise[(size_t)(t0 + r) * NE + c * 4]);
    float* dn = &ns[r * 65 + c * 4];
    dn[0] = u.x; dn[1] = u.y; dn[2] = u.z; dn[3] = u.w;
  }
  // stage w2 transposed
#pragma unroll
  for (int j = 0; j < 32; ++j) {
    const int i = tid + TB * j;  // 0..4095
    const int ep = i >> 6;       // row of w2 (e')
    const int e = i & 63;        // col of w2 (e)
    w2t[e * NE + ep] = w2[i];
  }
  if (tid < NE) hist[tid] = 0;
  __syncthreads();

  // logits for token t0+tid : acc[e'] = sum_e h[t][e] * w2[e'][e]
  float acc[NE];
#pragma unroll
  for (int j = 0; j < NE; ++j) acc[j] = 0.f;
  for (int e = 0; e < NE; ++e) {
    const float he = hs[tid * 65 + e];
    const float4* wrow = reinterpret_cast<const float4*>(&w2t[e * NE]);
#pragma unroll
    for (int q = 0; q < 16; ++q) {
      const float4 w = wrow[q];
      acc[q * 4 + 0] = fmaf(he, w.x, acc[q * 4 + 0]);
      acc[q * 4 + 1] = fmaf(he, w.y, acc[q * 4 + 1]);
      acc[q * 4 + 2] = fmaf(he, w.z, acc[q * 4 + 2]);
      acc[q * 4 + 3] = fmaf(he, w.w, acc[q * 4 + 3]);
    }
  }

  // argmax of logits + noise (first max wins, matching np.argmax)
  float best = -INFINITY;
  int bi = 0;
#pragma unroll
  for (int e = 0; e < NE; ++e) {
    const float v = acc[e] + ns[tid * 65 + e];
    if (v > best) { best = v; bi = e; }
  }
  out_idx[t0 + tid] = (float)bi;
  out_score[t0 + tid] = best;
  atomicAdd(&hist[bi], 1);

  // softmax (scores) in-place in acc
  float mx = -INFINITY;
#pragma unroll
  for (int e = 0; e < NE; ++e) mx = fmaxf(mx, acc[e]);
  float s = 0.f;
#pragma unroll
  for (int e = 0; e < NE; ++e) {
    acc[e] = expf(acc[e] - mx);
    s += acc[e];
  }
  const float inv = 1.f / s;
  // write scores into hs (own row only; safe: no other thread reads row tid)
#pragma unroll
  for (int e = 0; e < NE; ++e) hs[tid * 65 + e] = acc[e] * inv;
  __syncthreads();

  // column sums of scores: thread (e = tid&63, half = tid>>6) sums 64 rows
  {
    const int e = tid & 63;
    const int half = tid >> 6;
    float sum = 0.f;
    for (int r = half * 64; r < half * 64 + 64; ++r) sum += hs[r * 65 + e];
    ns[tid] = sum;  // ns no longer needed
    __syncthreads();
    if (tid < NE) {
      const float tot = ns[tid] + ns[tid + 64];
      imp_part[blockIdx.x * NE + tid] = tot;
      load_part[blockIdx.x * NE + tid] = (float)hist[tid];
    }
  }
}

// ---------------- Kernel C: finalize ----------------
__global__ void finalize_kernel(const float* __restrict__ imp_part,
                                const float* __restrict__ load_part,
                                float* __restrict__ out) {
  const int e = threadIdx.x;  // 64 threads, 1 wave
  float imp = 0.f, ld = 0.f;
  for (int b = 0; b < TOKENS / TB; ++b) {
    imp += imp_part[b * NE + e];
    ld += load_part[b * NE + e];
  }
  const float imp_mean = imp / (float)TOKENS;
  const float load_mean = ld / (float)TOKENS;
  out[2 * TOKENS + 1 + e] = load_mean;
  out[2 * TOKENS + 1 + NE + e] = imp_mean;
  float prod = imp_mean * load_mean;
#pragma unroll
  for (int off = 32; off > 0; off >>= 1) prod += __shfl_down(prod, off);
  if (e == 0) out[2 * TOKENS] = (float)NE * prod * BALW;
}

// ---------------- launch ----------------
extern "C" void kernel_launch(void* const* d_in, const int* in_sizes, int n_in,
                              void* d_out, int out_size, void* d_ws,
                              size_t ws_size, hipStream_t stream) {
  const float* x = (const float*)d_in[0];
  const float* w1 = (const float*)d_in[1];
  const float* w2 = (const float*)d_in[2];
  const float* noise = (const float*)d_in[3];
  float* out = (float*)d_out;

  float* h = (float*)d_ws;                        // 32768*64 f32 = 8 MB
  float* imp_part = h + (size_t)TOKENS * NE;      // 256*64 f32
  float* load_part = imp_part + (TOKENS / TB) * NE;

  hipLaunchKernelGGL(gemm_tanh_kernel, dim3(TOKENS / TM), dim3(256), 0, stream,
                     x, w1, h);
  hipLaunchKernelGGL(gate_kernel, dim3(TOKENS / TB), dim3(TB), 0, stream, h,
                     w2, noise, out, out + TOKENS, imp_part, load_part);
  hipLaunchKernelGGL(finalize_kernel, dim3(1), dim3(64), 0, stream, imp_part,
                     load_part, out);
}

// Round 2
// 970.155 us; speedup vs baseline: 1.2880x; 1.2880x over previous
//
#include <hip/hip_runtime.h>
#include <math.h>

// Problem constants
#define TOKENS 32768
#define DM 4096
#define NE 64
#define BALW 0.1f

// ================= Kernel A: partial GEMM (pre-tanh) =================
// grid = (TOKENS/TMA) * SPLITK = 256*2 = 512 blocks -> 2 blocks/CU,
// 8 waves/CU (2/SIMD). Per-thread 8m x 4n. As is k-major (stride 132)
// so A-frag = 2x ds_read_b128, conflict-free (start banks 4k+8ty+4s
// cover all 32). B-frag = 4x b32, 2-way (free).
#define TMA 128
#define BKA 32
#define SPLITK 2
#define KS (DM / SPLITK)  // 2048
#define LDSA (TMA + 4)    // 132: keeps b128 16B-alignment, spreads banks
#define LDSW 33

__global__ __launch_bounds__(256, 2) void gemm_partial_kernel(
    const float* __restrict__ x, const float* __restrict__ w1,
    float* __restrict__ hp) {
  __shared__ float As[BKA * LDSA];  // 16.9 KB
  __shared__ float Ws[NE * LDSW];   // 8.4 KB
  const int tid = threadIdx.x;
  const int mb = blockIdx.x >> 1;
  const int kz = blockIdx.x & 1;
  const int row0 = mb * TMA;
  const int kbase = kz * KS;
  const int ty = tid >> 4;  // 0..15
  const int tx = tid & 15;  // 0..15
  const int m0 = ty * 8;
  const int n0 = tx * 4;

  float acc[8][4];
#pragma unroll
  for (int i = 0; i < 8; ++i)
#pragma unroll
    for (int j = 0; j < 4; ++j) acc[i][j] = 0.f;

  for (int kc = kbase; kc < kbase + KS; kc += BKA) {
    __syncthreads();
    // stage x tile [TMA x BKA] -> k-major As. 8 lanes cover 128B of a row.
#pragma unroll
    for (int it = 0; it < 4; ++it) {
      const int f = tid + 256 * it;  // 0..1023 float4s
      const int k4 = f & 7;
      const int t = f >> 3;
      const float4 v = *reinterpret_cast<const float4*>(
          &x[(size_t)(row0 + t) * DM + kc + k4 * 4]);
      As[(k4 * 4 + 0) * LDSA + t] = v.x;
      As[(k4 * 4 + 1) * LDSA + t] = v.y;
      As[(k4 * 4 + 2) * LDSA + t] = v.z;
      As[(k4 * 4 + 3) * LDSA + t] = v.w;
    }
    // stage w1 tile [64 x BKA] row-major
#pragma unroll
    for (int q = 0; q < 2; ++q) {
      const int f = tid + 256 * q;  // 0..511 float4s
      const int c = f & 7;
      const int r = f >> 3;
      const float4 v = *reinterpret_cast<const float4*>(
          &w1[(size_t)r * DM + kc + c * 4]);
      float* d = &Ws[r * LDSW + c * 4];
      d[0] = v.x; d[1] = v.y; d[2] = v.z; d[3] = v.w;
    }
    __syncthreads();
#pragma unroll 8
    for (int k = 0; k < BKA; ++k) {
      const float4 a0 =
          *reinterpret_cast<const float4*>(&As[k * LDSA + m0]);
      const float4 a1 =
          *reinterpret_cast<const float4*>(&As[k * LDSA + m0 + 4]);
      float b[4];
#pragma unroll
      for (int j = 0; j < 4; ++j) b[j] = Ws[(n0 + j) * LDSW + k];
      const float a[8] = {a0.x, a0.y, a0.z, a0.w, a1.x, a1.y, a1.z, a1.w};
#pragma unroll
      for (int i = 0; i < 8; ++i)
#pragma unroll
        for (int j = 0; j < 4; ++j) acc[i][j] = fmaf(a[i], b[j], acc[i][j]);
    }
  }
  float* dst = hp + (size_t)kz * TOKENS * NE;
#pragma unroll
  for (int i = 0; i < 8; ++i) {
    const float4 v = make_float4(acc[i][0], acc[i][1], acc[i][2], acc[i][3]);
    *reinterpret_cast<float4*>(&dst[(size_t)(row0 + m0 + i) * NE + n0]) = v;
  }
}

// ================= Kernel B: gate =================
// 64 tokens/block, 256 threads, grid 512. Phase 0: combine split-K
// partials + tanh into hs, stage w2. Phase 1: logits GEMM (4x4/thread)
// into ls. Phase 2: softmax/argmax per token (1 wave). Phase 3: column
// sums -> per-block partials.
#define TG 64

__global__ __launch_bounds__(256) void gate_kernel(
    const float* __restrict__ hp, const float* __restrict__ w2,
    const float* __restrict__ noise, float* __restrict__ out_idx,
    float* __restrict__ out_score, float* __restrict__ imp_part,
    float* __restrict__ load_part) {
  __shared__ float hs[TG * 65];   // 16.6 KB
  __shared__ float w2s[NE * 65];  // 16.6 KB
  __shared__ float ls[TG * 66];   // 16.9 KB
  __shared__ float csum[2 * NE];
  __shared__ int hist[NE];
  const int tid = threadIdx.x;
  const int t0 = blockIdx.x * TG;
  if (tid < NE) hist[tid] = 0;

  // stage hs = tanh(hp0 + hp1): 64*16 float4s, 4/thread
#pragma unroll
  for (int it = 0; it < 4; ++it) {
    const int f = tid + 256 * it;  // 0..1023
    const int c = f & 15;
    const int t = f >> 4;
    const size_t g = (size_t)(t0 + t) * NE + c * 4;
    const float4 p0 = *reinterpret_cast<const float4*>(&hp[g]);
    const float4 p1 =
        *reinterpret_cast<const float4*>(&hp[(size_t)TOKENS * NE + g]);
    float* d = &hs[t * 65 + c * 4];
    d[0] = tanhf(p0.x + p1.x);
    d[1] = tanhf(p0.y + p1.y);
    d[2] = tanhf(p0.z + p1.z);
    d[3] = tanhf(p0.w + p1.w);
  }
  // stage w2 [64x64]
#pragma unroll
  for (int it = 0; it < 4; ++it) {
    const int f = tid + 256 * it;  // 0..1023
    const int c = f & 15;
    const int r = f >> 4;
    const float4 v =
        *reinterpret_cast<const float4*>(&w2[(size_t)r * NE + c * 4]);
    float* d = &w2s[r * 65 + c * 4];
    d[0] = v.x; d[1] = v.y; d[2] = v.z; d[3] = v.w;
  }
  __syncthreads();

  // phase 1: logits = hs @ w2s^T (over k=expert-in), 4x4 per thread
  {
    const int m0 = (tid >> 4) * 4;
    const int n0 = (tid & 15) * 4;
    float acc[4][4];
#pragma unroll
    for (int i = 0; i < 4; ++i)
#pragma unroll
      for (int j = 0; j < 4; ++j) acc[i][j] = 0.f;
#pragma unroll 8
    for (int k = 0; k < NE; ++k) {
      float a[4], b[4];
#pragma unroll
      for (int i = 0; i < 4; ++i) a[i] = hs[(m0 + i) * 65 + k];
#pragma unroll
      for (int j = 0; j < 4; ++j) b[j] = w2s[(n0 + j) * 65 + k];
#pragma unroll
      for (int i = 0; i < 4; ++i)
#pragma unroll
        for (int j = 0; j < 4; ++j) acc[i][j] = fmaf(a[i], b[j], acc[i][j]);
    }
#pragma unroll
    for (int i = 0; i < 4; ++i)
#pragma unroll
      for (int j = 0; j < 4; ++j) ls[(m0 + i) * 66 + n0 + j] = acc[i][j];
  }
  __syncthreads();

  // phase 2: per-token softmax + gumbel argmax (1 wave)
  if (tid < TG) {
    const int t = tid;
    float mx = -INFINITY, best = -INFINITY;
    int bi = 0;
    for (int e = 0; e < NE; ++e) {
      const float l = ls[t * 66 + e];
      mx = fmaxf(mx, l);
      const float g = l + noise[(size_t)(t0 + t) * NE + e];
      if (g > best) { best = g; bi = e; }
    }
    float s = 0.f;
    for (int e = 0; e < NE; ++e) {
      const float ex = expf(ls[t * 66 + e] - mx);
      s += ex;
      ls[t * 66 + e] = ex;
    }
    const float inv = 1.f / s;
    for (int e = 0; e < NE; ++e) ls[t * 66 + e] *= inv;
    out_idx[t0 + t] = (float)bi;
    out_score[t0 + t] = best;
    atomicAdd(&hist[bi], 1);
  }
  __syncthreads();

  // phase 3: column sums of scores
  if (tid < 128) {
    const int e = tid & 63;
    const int half = tid >> 6;
    float s = 0.f;
    for (int r = half * 32; r < half * 32 + 32; ++r) s += ls[r * 66 + e];
    csum[half * NE + e] = s;
  }
  __syncthreads();
  if (tid < NE) {
    imp_part[(size_t)blockIdx.x * NE + tid] = csum[tid] + csum[NE + tid];
    load_part[(size_t)blockIdx.x * NE + tid] = (float)hist[tid];
  }
}

// ================= Kernel C: finalize =================
#define GBLOCKS (TOKENS / TG)  // 512

__global__ void finalize_kernel(const float* __restrict__ imp_part,
                                const float* __restrict__ load_part,
                                float* __restrict__ out) {
  const int e = threadIdx.x;  // 64 threads, 1 wave
  float imp = 0.f, ld = 0.f;
  for (int b = 0; b < GBLOCKS; ++b) {
    imp += imp_part[(size_t)b * NE + e];
    ld += load_part[(size_t)b * NE + e];
  }
  const float imp_mean = imp / (float)TOKENS;
  const float load_mean = ld / (float)TOKENS;
  out[2 * TOKENS + 1 + e] = load_mean;
  out[2 * TOKENS + 1 + NE + e] = imp_mean;
  float prod = imp_mean * load_mean;
#pragma unroll
  for (int off = 32; off > 0; off >>= 1) prod += __shfl_down(prod, off);
  if (e == 0) out[2 * TOKENS] = (float)NE * prod * BALW;
}

// ================= launch =================
extern "C" void kernel_launch(void* const* d_in, const int* in_sizes, int n_in,
                              void* d_out, int out_size, void* d_ws,
                              size_t ws_size, hipStream_t stream) {
  const float* x = (const float*)d_in[0];
  const float* w1 = (const float*)d_in[1];
  const float* w2 = (const float*)d_in[2];
  const float* noise = (const float*)d_in[3];
  float* out = (float*)d_out;

  float* hp = (float*)d_ws;  // SPLITK * 32768 * 64 f32 = 16.8 MB
  float* imp_part = hp + (size_t)SPLITK * TOKENS * NE;  // 512*64
  float* load_part = imp_part + (size_t)GBLOCKS * NE;   // 512*64

  hipLaunchKernelGGL(gemm_partial_kernel, dim3((TOKENS / TMA) * SPLITK),
                     dim3(256), 0, stream, x, w1, hp);
  hipLaunchKernelGGL(gate_kernel, dim3(GBLOCKS), dim3(256), 0, stream, hp, w2,
                     noise, out, out + TOKENS, imp_part, load_part);
  hipLaunchKernelGGL(finalize_kernel, dim3(1), dim3(64), 0, stream, imp_part,
                     load_part, out);
}